// Round 14
// baseline (360.598 us; speedup 1.0000x reference)
//
#include <hip/hip_runtime.h>
#include <hip/hip_bf16.h>

// MHA fwd: B=4,S=2048,D=1024,H=16,DK=DV=64, causal.
// v15: v12 baseline (313.4us best) + split-K=2 O-projection.
//  R13: v14 persistent-qkv regressed (occ 17%, rolling dispatch beats pinned
//  3/CU) -> qkv locked at v9-exact (107us, its 2-phase plateau).
//  Accounting pins gemm_bb ~100us (~170 TF): N=1024 -> 512 blocks (2/CU at
//  64KB dbuf), K=1024 -> 16 serial drain-exposed iters.  v15: 1024 blocks =
//  2 k-slices x 512 tiles, v9-style single-buffer body over K=512 (8 iters,
//  32KB LDS -> 4/CU all resident), fp32 atomicAdd combine into memset-zeroed
//  d_out (commutative -> deterministic; pairwise contention only).
//  qkv / attn_k / transpose_w4: v12 versions verbatim.

typedef __attribute__((ext_vector_type(8))) __bf16 bf16x8;
typedef __attribute__((ext_vector_type(8))) unsigned short ushort8v;
typedef __attribute__((ext_vector_type(4))) unsigned short ushort4v;
typedef __attribute__((ext_vector_type(4))) unsigned uint4v;
typedef __attribute__((ext_vector_type(2))) unsigned uint2v;
typedef __attribute__((ext_vector_type(4))) float float4v;

#define MFMA16(a, b, c) __builtin_amdgcn_mfma_f32_16x16x32_bf16((a), (b), (c), 0, 0, 0)
#define GLDS16(g, l)                                                     \
    __builtin_amdgcn_global_load_lds(                                    \
        (const __attribute__((address_space(1))) void*)(g),              \
        (__attribute__((address_space(3))) void*)(l), 16, 0, 0)

__device__ __forceinline__ unsigned short f2bf(float f) {   // RNE
    union { float f; unsigned u; } v; v.f = f;
    unsigned r = v.u + 0x7fffu + ((v.u >> 16) & 1u);
    return (unsigned short)(r >> 16);
}
__device__ __forceinline__ unsigned pkbf(float a, float b) { // 2xf32 -> 2xbf16
    union { float f; unsigned u; } x, y; x.f = a; y.f = b;
    return __builtin_amdgcn_perm(y.u + 0x8000u, x.u + 0x8000u, 0x07060302u);
}
__device__ __forceinline__ float exp2_fast(float x) {
#if __has_builtin(__builtin_amdgcn_exp2f)
    return __builtin_amdgcn_exp2f(x);
#else
    return __builtin_exp2f(x);
#endif
}

// ---------------------------------------------------------------------------
// 4x W [K=1024][N=1024] fp32 -> Wt [N][K] bf16 (scale folded), one launch
__global__ __launch_bounds__(256) void transpose_w4(
    const float* __restrict__ W0, const float* __restrict__ W1,
    const float* __restrict__ W2, const float* __restrict__ W3,
    unsigned short* __restrict__ T0, unsigned short* __restrict__ T1,
    unsigned short* __restrict__ T2, unsigned short* __restrict__ T3)
{
    __shared__ unsigned short T[64][72];
    const int z = blockIdx.z;
    const float* W = z == 0 ? W0 : z == 1 ? W1 : z == 2 ? W2 : W3;
    unsigned short* Wt = z == 0 ? T0 : z == 1 ? T1 : z == 2 ? T2 : T3;
    const float scale = (z == 1) ? 0.125f * 1.44269504088896f : 1.0f; // K: softmax*log2e
    const int t = threadIdx.x;
    const int n0 = blockIdx.x * 64, k0 = blockIdx.y * 64;
    for (int i = 0; i < 4; i++) {
        int idx = i * 256 + t, r = idx >> 4, c = (idx & 15) * 4;
        float4v v = *(const float4v*)&W[(size_t)(k0 + r) * 1024 + n0 + c];
        T[c + 0][r] = f2bf(v.x * scale); T[c + 1][r] = f2bf(v.y * scale);
        T[c + 2][r] = f2bf(v.z * scale); T[c + 3][r] = f2bf(v.w * scale);
    }
    __syncthreads();
    for (int i = 0; i < 4; i++) {
        int idx = i * 256 + t, r = idx >> 4, c = (idx & 15) * 4;
        ushort4v o; o.x = T[r][c]; o.y = T[r][c + 1]; o.z = T[r][c + 2]; o.w = T[r][c + 3];
        *(ushort4v*)&Wt[(size_t)(n0 + r) * 1024 + k0 + c] = o;
    }
}

// ---------------------------------------------------------------------------
// Grouped QKV projection — v9 VERBATIM (verified 107us, bank-conflicts 0).
// ---------------------------------------------------------------------------
__global__ __launch_bounds__(256) void qkv_gemm(
    const float* __restrict__ Aq, const float* __restrict__ Ak,
    const float* __restrict__ Av,
    const unsigned short* __restrict__ WQt, const unsigned short* __restrict__ WKt,
    const unsigned short* __restrict__ WVt,
    unsigned short* __restrict__ Qb, unsigned short* __restrict__ Kb,
    unsigned short* __restrict__ Vto)
{
    __shared__ __align__(16) unsigned short As[128 * 64];
    __shared__ __align__(16) unsigned short Bs[128 * 64];

    const int t = threadIdx.x;
    const int lane = t & 63, w = t >> 6;
    const int lanelo = lane & 15, quad = lane >> 4;
    const int wm = w >> 1, wn = w & 1;
    const int rsw = (lanelo & 7) << 3;     // read-side XOR (elements)

    const int d = blockIdx.x;
    const int xcd = d & 7;
    const int s = d >> 3;                  // 0..191
    const int group = s >> 6;              // 0,1,2
    const int u = s & 63;
    const bool vsw = (group == 2);

    const float* act; const unsigned short* wt; unsigned short* out;
    if (group == 0)      { act = Aq; wt = WQt; out = Qb; }
    else if (group == 1) { act = Ak; wt = WKt; out = Kb; }
    else                 { act = Av; wt = WVt; out = Vto; }

    const int big = (((u >> 3) << 3) | xcd) * 128;   // activation-panel tile
    const int sml = (u & 7) * 128;                   // other-operand tile
    int m0, n0, ldc;
    if (!vsw) { m0 = big; n0 = sml; ldc = 1024; }
    else      { n0 = big; m0 = sml; ldc = 8192; }
    const int act0 = vsw ? n0 : m0;      // activation tile row base
    const int wt0  = vsw ? m0 : n0;      // weight tile row base
    unsigned short* actS = vsw ? Bs : As;
    unsigned short* wtS  = vsw ? As : Bs;

    float4v acc[4][4];
    for (int i = 0; i < 4; i++)
        for (int j = 0; j < 4; j++) acc[i][j] = (float4v)(0.f);

    for (int k0 = 0; k0 < 1024; k0 += 64) {
        // weight tile via async glds, source pre-swizzled (linear LDS dest)
        for (int i = 0; i < 4; i++) {
            int idx = i * 256 + t, row = idx >> 3, ch = idx & 7;
            GLDS16(wt + (size_t)(wt0 + row) * 1024 + k0 + ((ch ^ (row & 7)) << 3),
                   &wtS[idx * 8]);
        }
        // activation tile: fp32 -> bf16 reg-staged, ds_write to swizzled slot
        for (int i = 0; i < 4; i++) {
            int si = i * 256 + t, row = si >> 3, ch = si & 7;
            const float* ap = act + (size_t)(act0 + row) * 1024 + k0 + ch * 8;
            float4v x = *(const float4v*)ap;
            float4v y = *(const float4v*)(ap + 4);
            uint4v o4 = { pkbf(x.x, x.y), pkbf(x.z, x.w),
                          pkbf(y.x, y.y), pkbf(y.z, y.w) };
            *(uint4v*)&actS[row * 64 + ((ch ^ (row & 7)) << 3)] = o4;
        }
        __syncthreads();
        for (int ks = 0; ks < 2; ks++) {
            bf16x8 af[4], bfr[4];
            for (int mi = 0; mi < 4; mi++)
                af[mi] = *(const bf16x8*)
                    &As[(wm * 64 + mi * 16 + lanelo) * 64 + ((ks * 32 + quad * 8) ^ rsw)];
            for (int ni = 0; ni < 4; ni++)
                bfr[ni] = *(const bf16x8*)
                    &Bs[(wn * 64 + ni * 16 + lanelo) * 64 + ((ks * 32 + quad * 8) ^ rsw)];
            for (int mi = 0; mi < 4; mi++)
                for (int ni = 0; ni < 4; ni++)
                    acc[mi][ni] = MFMA16(af[mi], bfr[ni], acc[mi][ni]);
        }
        __syncthreads();
    }

    for (int mi = 0; mi < 4; mi++)
        for (int ni = 0; ni < 4; ni++) {
            int col = n0 + wn * 64 + ni * 16 + lanelo;
            for (int rr = 0; rr < 4; rr++) {
                int row = m0 + wm * 64 + mi * 16 + quad * 4 + rr;
                out[(size_t)row * ldc + col] = f2bf(acc[mi][ni][rr]);
            }
        }
}

// ---------------------------------------------------------------------------
// O-projection, split-K=2: C[8192,1024] fp32 += A[.,kslice]bf16 @ Bt^T.
// 1024 blocks = 2 k-slices x (64 m-panels x 8 n-tiles).  v9-style single-
// buffer 2-barrier body over 8 K-iters, 32KB LDS -> 4 blocks/CU, all
// resident.  fp32 atomicAdd into memset-zeroed d_out: commutative ->
// deterministic result (x+y) regardless of slice arrival order.
// ---------------------------------------------------------------------------
__global__ __launch_bounds__(256) void gemm_bb_sk(
    const unsigned short* __restrict__ A, const unsigned short* __restrict__ Bt,
    float* __restrict__ Cp, int M, int N, int K)
{
    __shared__ __align__(16) unsigned short As[128 * 64];
    __shared__ __align__(16) unsigned short Bs[128 * 64];

    const int t = threadIdx.x;
    const int lane = t & 63, w = t >> 6;
    const int lanelo = lane & 15, quad = lane >> 4;
    const int wm = w >> 1, wn = w & 1;
    const int rsw = (lanelo & 7) << 3;

    const int d = blockIdx.x;                        // 0..1023
    const int xcd = d & 7, s = d >> 3;               // s: 0..127
    const int ksl = s >> 6;                          // k-slice 0/1
    const int u = s & 63;
    const int m0 = (((u >> 3) << 3) | xcd) * 128;    // 64 m-panels -> XCD
    const int n0 = (u & 7) * 128;                    // 8 n-tiles
    const int kbeg = ksl * 512;

    float4v acc[4][4];
    for (int i = 0; i < 4; i++)
        for (int j = 0; j < 4; j++) acc[i][j] = (float4v)(0.f);

    for (int kk = 0; kk < 512; kk += 64) {
        const int k0 = kbeg + kk;
        for (int i = 0; i < 4; i++) {
            int idx = i * 256 + t, row = idx >> 3, ch = idx & 7;
            GLDS16(A + (size_t)(m0 + row) * K + k0 + ((ch ^ (row & 7)) << 3),
                   &As[idx * 8]);
        }
        for (int i = 0; i < 4; i++) {
            int idx = i * 256 + t, row = idx >> 3, ch = idx & 7;
            GLDS16(Bt + (size_t)(n0 + row) * K + k0 + ((ch ^ (row & 7)) << 3),
                   &Bs[idx * 8]);
        }
        __syncthreads();
        for (int ks = 0; ks < 2; ks++) {
            bf16x8 af[4], bfr[4];
            for (int mi = 0; mi < 4; mi++)
                af[mi] = *(const bf16x8*)
                    &As[(wm * 64 + mi * 16 + lanelo) * 64 + ((ks * 32 + quad * 8) ^ rsw)];
            for (int ni = 0; ni < 4; ni++)
                bfr[ni] = *(const bf16x8*)
                    &Bs[(wn * 64 + ni * 16 + lanelo) * 64 + ((ks * 32 + quad * 8) ^ rsw)];
            for (int mi = 0; mi < 4; mi++)
                for (int ni = 0; ni < 4; ni++)
                    acc[mi][ni] = MFMA16(af[mi], bfr[ni], acc[mi][ni]);
        }
        __syncthreads();
    }

    for (int mi = 0; mi < 4; mi++)
        for (int ni = 0; ni < 4; ni++) {
            int col = n0 + wn * 64 + ni * 16 + lanelo;
            for (int r = 0; r < 4; r++) {
                int row = m0 + wm * 64 + mi * 16 + quad * 4 + r;
                atomicAdd(&Cp[(size_t)row * N + col], acc[mi][ni][r]);
            }
        }
}

// ---------------------------------------------------------------------------
// Flash causal attention — v12 (counted vmcnt + raw barriers), kept.
// ---------------------------------------------------------------------------
__global__ __launch_bounds__(256, 4) void attn_k(
    const unsigned short* __restrict__ Qb, const unsigned short* __restrict__ Kb,
    const unsigned short* __restrict__ Vt, unsigned short* __restrict__ Ob)
{
    __shared__ __align__(16) unsigned short Ks[2][64 * 64];
    __shared__ __align__(16) unsigned short Vs[2][64 * 64];
    __shared__ __align__(16) unsigned short Ps[4][16 * 64];

    const int t = threadIdx.x;
    const int lane = t & 63, w = t >> 6;
    const int lanelo = lane & 15, quad = lane >> 4;
    const int bh = blockIdx.x;                  // same (b,h) -> same XCD
    const int b = bh >> 4, h = bh & 15;

    unsigned short* pw = &Ps[w][0];
    const int rsw = (lanelo & 7) * 8;           // K/V read XOR (elems)
    const int l7 = lanelo & 7;                  // Ps chunk XOR key

    auto stage = [&](int buf, int kt) {         // 4 glds / thread
        for (int i = 0; i < 2; i++) {
            int idx = i * 256 + t, row = idx >> 3, ch = idx & 7;
            GLDS16(Kb + ((size_t)(b * 2048 + kt * 64 + row)) * 1024 + h * 64
                       + ((ch ^ (row & 7)) << 3),
                   &Ks[buf][idx * 8]);
        }
        for (int i = 0; i < 2; i++) {
            int idx = i * 256 + t, row = idx >> 3, ch = idx & 7;
            GLDS16(Vt + (size_t)(h * 64 + row) * 8192 + b * 2048 + kt * 64
                       + ((ch ^ (row & 7)) << 3),
                   &Vs[buf][idx * 8]);
        }
    };

    for (int half = 0; half < 2; half++) {
        const int qt = half ? blockIdx.y : 31 - blockIdx.y;
        const int qb = qt * 64;
        const int nkt = qt + 1;
        const int q = qb + w * 16 + lanelo;

        bf16x8 qf[2];
        {
            const unsigned short* qp = Qb + ((size_t)(b * 2048) + q) * 1024 + h * 64 + quad * 8;
            qf[0] = *(const bf16x8*)(qp);
            qf[1] = *(const bf16x8*)(qp + 32);
        }
        float4v o[4];
        for (int i = 0; i < 4; i++) o[i] = (float4v)(0.f);
        float m_ = -__builtin_inff(), l_ = 0.f;

        stage(0, 0);

        int cur = 0;
        for (int kt = 0; kt < nkt; kt++) {
            if (kt + 1 < nkt) {
                stage(cur ^ 1, kt + 1);                  // prefetch next tile
                asm volatile("s_waitcnt vmcnt(4)" ::: "memory");  // cur ready
            } else {
                asm volatile("s_waitcnt vmcnt(0)" ::: "memory");
            }
            __builtin_amdgcn_s_barrier();
            __builtin_amdgcn_sched_barrier(0);

            const unsigned short* ks = &Ks[cur][0];
            const unsigned short* vs = &Vs[cur][0];

            // S^T tiles: A = K rows (m=key), B = Q rows (n=q)
            float4v sc[4];
            for (int nt = 0; nt < 4; nt++) {
                sc[nt] = (float4v)(0.f);
                for (int c = 0; c < 2; c++) {
                    bf16x8 kf = *(const bf16x8*)
                        &ks[(nt * 16 + lanelo) * 64 + ((c * 32 + quad * 8) ^ rsw)];
                    sc[nt] = MFMA16(kf, qf[c], sc[nt]);
                }
            }
            if (kt == nkt - 1) {                        // only diagonal needs mask
                const int kb0 = qb + quad * 4;
                for (int nt = 0; nt < 4; nt++)
                    for (int r = 0; r < 4; r++)
                        if (kb0 + nt * 16 + r > q) sc[nt][r] = -__builtin_inff();
            }
            float mx = sc[0][0];
            for (int nt = 0; nt < 4; nt++)
                for (int r = 0; r < 4; r++) mx = fmaxf(mx, sc[nt][r]);
            mx = fmaxf(mx, __shfl_xor(mx, 16, 64));
            mx = fmaxf(mx, __shfl_xor(mx, 32, 64));
            if (!__all(mx <= m_ + 8.f)) {               // defer-max (T13), log2 dom
                float mnew = fmaxf(m_, mx);
                float alpha = exp2_fast(m_ - mnew);
                l_ *= alpha;
                for (int vt = 0; vt < 4; vt++)
                    for (int r = 0; r < 4; r++) o[vt][r] *= alpha;
                m_ = mnew;
            }
            float rs = 0.f;
            for (int nt = 0; nt < 4; nt++)
                for (int r = 0; r < 4; r++) {
                    float e = exp2_fast(sc[nt][r] - m_);
                    sc[nt][r] = e; rs += e;
                }
            rs += __shfl_xor(rs, 16, 64);
            rs += __shfl_xor(rs, 32, 64);
            l_ += rs;

            // P^T -> Ps (swizzled 16B chunks), b64 writes
            for (int nt = 0; nt < 4; nt++) {
                uint2v pv;
                pv.x = pkbf(sc[nt][0], sc[nt][1]);
                pv.y = pkbf(sc[nt][2], sc[nt][3]);
                *(uint2v*)((char*)pw + lanelo * 128
                           + ((((nt << 1) | (quad >> 1)) ^ l7) << 4)
                           + ((quad & 1) << 3)) = pv;
            }
            asm volatile("s_waitcnt lgkmcnt(0)" ::: "memory");
            __builtin_amdgcn_sched_barrier(0);
            // O^T += V^T P^T : A = V^T (m=dv), B = P (n=q)
            for (int c = 0; c < 2; c++) {
                bf16x8 pf = *(const bf16x8*)((const char*)pw + lanelo * 128
                                             + (((c * 4 + quad) ^ l7) << 4));
                for (int vt = 0; vt < 4; vt++) {
                    bf16x8 vf = *(const bf16x8*)
                        &vs[(vt * 16 + lanelo) * 64 + ((c * 32 + quad * 8) ^ rsw)];
                    o[vt] = MFMA16(vf, pf, o[vt]);
                }
            }
            __builtin_amdgcn_sched_barrier(0);
            __builtin_amdgcn_s_barrier();               // reads done before restage
            cur ^= 1;
        }

        // epilogue: normalize, transpose O^T -> O via swizzled Ps, 16B stores
        float inv = 1.0f / l_;
        for (int vt = 0; vt < 4; vt++) {
            uint2v ov;
            ov.x = pkbf(o[vt][0] * inv, o[vt][1] * inv);
            ov.y = pkbf(o[vt][2] * inv, o[vt][3] * inv);
            *(uint2v*)((char*)pw + lanelo * 128
                       + ((((vt << 1) | (quad >> 1)) ^ l7) << 4)
                       + ((quad & 1) << 3)) = ov;
        }
        asm volatile("s_waitcnt lgkmcnt(0)" ::: "memory");
        __builtin_amdgcn_sched_barrier(0);
        for (int i = 0; i < 2; i++) {
            int qr = i * 8 + (lane >> 3);
            int ch = lane & 7;
            ushort8v ov = *(const ushort8v*)((const char*)pw + qr * 128
                                             + ((ch ^ (qr & 7)) << 4));
            *(ushort8v*)(Ob + ((size_t)(b * 2048) + qb + w * 16 + qr) * 1024
                         + h * 64 + ch * 8) = ov;
        }
    }
}

// ---------------------------------------------------------------------------
extern "C" void kernel_launch(void* const* d_in, const int* in_sizes, int n_in,
                              void* d_out, int out_size, void* d_ws, size_t ws_size,
                              hipStream_t stream) {
    const float* queries = (const float*)d_in[0];
    const float* keys    = (const float*)d_in[1];
    const float* values  = (const float*)d_in[2];
    // d_in[3] = causal mask, handled analytically
    const float* W_Q = (const float*)d_in[4];
    const float* W_K = (const float*)d_in[5];
    const float* W_V = (const float*)d_in[6];
    const float* W_O = (const float*)d_in[7];

    const size_t SZ = (size_t)4 * 2048 * 1024;        // 8.4M elems
    const size_t WSZ = (size_t)1024 * 1024;
    unsigned short* Qb  = (unsigned short*)d_ws;
    unsigned short* Kb  = Qb + SZ;
    unsigned short* Vt  = Kb + SZ;                    // [1024][8192]
    unsigned short* Ab  = Vt + SZ;                    // attn output
    unsigned short* WQt = Ab + SZ;
    unsigned short* WKt = WQt + WSZ;
    unsigned short* WVt = WKt + WSZ;
    unsigned short* WOt = WVt + WSZ;                  // ~75.5 MB total

    dim3 blk(256);
    hipLaunchKernelGGL(transpose_w4, dim3(16, 16, 4), blk, 0, stream,
                       W_Q, W_K, W_V, W_O, WQt, WKt, WVt, WOt);

    hipLaunchKernelGGL(qkv_gemm, dim3(1536), blk, 0, stream,
                       queries, keys, values, WQt, WKt, WVt, Qb, Kb, Vt);

    hipLaunchKernelGGL(attn_k, dim3(64, 16), blk, 0, stream, Qb, Kb, Vt, Ab);

    // split-K O-projection: zero the fp32 output, then 2 slices atomicAdd
    hipMemsetAsync(d_out, 0, (size_t)8192 * 1024 * sizeof(float), stream);
    hipLaunchKernelGGL(gemm_bb_sk, dim3(1024), blk, 0, stream,
                       Ab, WOt, (float*)d_out, 8192, 1024, 1024);
}

// Round 15
// 323.178 us; speedup vs baseline: 1.1158x; 1.1158x over previous
//
#include <hip/hip_runtime.h>
#include <hip/hip_bf16.h>

// MHA fwd: B=4,S=2048,D=1024,H=16,DK=DV=64, causal.
// v16: v12 pipeline (313.4us verified best) + O-proj retiled 256x128/512thr.
//  R14: split-K atomics regressed (+47us of atomic RMW + memset) — reverted.
//  gemm_bb has never been directly measured (never in top-5); v16 both
//  optimizes and BOUNDS it: 256 blocks of 256x128 (8 waves 4Mx2N, 64x64
//  wave tile = v9 regs, no spill; launch_bounds(512,2) caps VGPR at 256 —
//  v13's spill came from (512,6)).  Exactly 1 block/CU, zero tail, 2-phase
//  dbuf + counted vmcnt(6) (6 glds/thread in flight), (row&7) swizzle.
//  Per-CU staging bytes/K-iter -25% vs v12's 2x128x128.
//  qkv (v9, 107us) / attn_k (v12, 74us) / transpose_w4 verbatim.

typedef __attribute__((ext_vector_type(8))) __bf16 bf16x8;
typedef __attribute__((ext_vector_type(8))) unsigned short ushort8v;
typedef __attribute__((ext_vector_type(4))) unsigned short ushort4v;
typedef __attribute__((ext_vector_type(4))) unsigned uint4v;
typedef __attribute__((ext_vector_type(2))) unsigned uint2v;
typedef __attribute__((ext_vector_type(4))) float float4v;

#define MFMA16(a, b, c) __builtin_amdgcn_mfma_f32_16x16x32_bf16((a), (b), (c), 0, 0, 0)
#define GLDS16(g, l)                                                     \
    __builtin_amdgcn_global_load_lds(                                    \
        (const __attribute__((address_space(1))) void*)(g),              \
        (__attribute__((address_space(3))) void*)(l), 16, 0, 0)

__device__ __forceinline__ unsigned short f2bf(float f) {   // RNE
    union { float f; unsigned u; } v; v.f = f;
    unsigned r = v.u + 0x7fffu + ((v.u >> 16) & 1u);
    return (unsigned short)(r >> 16);
}
__device__ __forceinline__ unsigned pkbf(float a, float b) { // 2xf32 -> 2xbf16
    union { float f; unsigned u; } x, y; x.f = a; y.f = b;
    return __builtin_amdgcn_perm(y.u + 0x8000u, x.u + 0x8000u, 0x07060302u);
}
__device__ __forceinline__ float exp2_fast(float x) {
#if __has_builtin(__builtin_amdgcn_exp2f)
    return __builtin_amdgcn_exp2f(x);
#else
    return __builtin_exp2f(x);
#endif
}

// ---------------------------------------------------------------------------
// 4x W [K=1024][N=1024] fp32 -> Wt [N][K] bf16 (scale folded), one launch
__global__ __launch_bounds__(256) void transpose_w4(
    const float* __restrict__ W0, const float* __restrict__ W1,
    const float* __restrict__ W2, const float* __restrict__ W3,
    unsigned short* __restrict__ T0, unsigned short* __restrict__ T1,
    unsigned short* __restrict__ T2, unsigned short* __restrict__ T3)
{
    __shared__ unsigned short T[64][72];
    const int z = blockIdx.z;
    const float* W = z == 0 ? W0 : z == 1 ? W1 : z == 2 ? W2 : W3;
    unsigned short* Wt = z == 0 ? T0 : z == 1 ? T1 : z == 2 ? T2 : T3;
    const float scale = (z == 1) ? 0.125f * 1.44269504088896f : 1.0f; // K: softmax*log2e
    const int t = threadIdx.x;
    const int n0 = blockIdx.x * 64, k0 = blockIdx.y * 64;
    for (int i = 0; i < 4; i++) {
        int idx = i * 256 + t, r = idx >> 4, c = (idx & 15) * 4;
        float4v v = *(const float4v*)&W[(size_t)(k0 + r) * 1024 + n0 + c];
        T[c + 0][r] = f2bf(v.x * scale); T[c + 1][r] = f2bf(v.y * scale);
        T[c + 2][r] = f2bf(v.z * scale); T[c + 3][r] = f2bf(v.w * scale);
    }
    __syncthreads();
    for (int i = 0; i < 4; i++) {
        int idx = i * 256 + t, r = idx >> 4, c = (idx & 15) * 4;
        ushort4v o; o.x = T[r][c]; o.y = T[r][c + 1]; o.z = T[r][c + 2]; o.w = T[r][c + 3];
        *(ushort4v*)&Wt[(size_t)(n0 + r) * 1024 + k0 + c] = o;
    }
}

// ---------------------------------------------------------------------------
// Grouped QKV projection — v9 VERBATIM (verified 107us, bank-conflicts 0).
// ---------------------------------------------------------------------------
__global__ __launch_bounds__(256) void qkv_gemm(
    const float* __restrict__ Aq, const float* __restrict__ Ak,
    const float* __restrict__ Av,
    const unsigned short* __restrict__ WQt, const unsigned short* __restrict__ WKt,
    const unsigned short* __restrict__ WVt,
    unsigned short* __restrict__ Qb, unsigned short* __restrict__ Kb,
    unsigned short* __restrict__ Vto)
{
    __shared__ __align__(16) unsigned short As[128 * 64];
    __shared__ __align__(16) unsigned short Bs[128 * 64];

    const int t = threadIdx.x;
    const int lane = t & 63, w = t >> 6;
    const int lanelo = lane & 15, quad = lane >> 4;
    const int wm = w >> 1, wn = w & 1;
    const int rsw = (lanelo & 7) << 3;     // read-side XOR (elements)

    const int d = blockIdx.x;
    const int xcd = d & 7;
    const int s = d >> 3;                  // 0..191
    const int group = s >> 6;              // 0,1,2
    const int u = s & 63;
    const bool vsw = (group == 2);

    const float* act; const unsigned short* wt; unsigned short* out;
    if (group == 0)      { act = Aq; wt = WQt; out = Qb; }
    else if (group == 1) { act = Ak; wt = WKt; out = Kb; }
    else                 { act = Av; wt = WVt; out = Vto; }

    const int big = (((u >> 3) << 3) | xcd) * 128;   // activation-panel tile
    const int sml = (u & 7) * 128;                   // other-operand tile
    int m0, n0, ldc;
    if (!vsw) { m0 = big; n0 = sml; ldc = 1024; }
    else      { n0 = big; m0 = sml; ldc = 8192; }
    const int act0 = vsw ? n0 : m0;      // activation tile row base
    const int wt0  = vsw ? m0 : n0;      // weight tile row base
    unsigned short* actS = vsw ? Bs : As;
    unsigned short* wtS  = vsw ? As : Bs;

    float4v acc[4][4];
    for (int i = 0; i < 4; i++)
        for (int j = 0; j < 4; j++) acc[i][j] = (float4v)(0.f);

    for (int k0 = 0; k0 < 1024; k0 += 64) {
        // weight tile via async glds, source pre-swizzled (linear LDS dest)
        for (int i = 0; i < 4; i++) {
            int idx = i * 256 + t, row = idx >> 3, ch = idx & 7;
            GLDS16(wt + (size_t)(wt0 + row) * 1024 + k0 + ((ch ^ (row & 7)) << 3),
                   &wtS[idx * 8]);
        }
        // activation tile: fp32 -> bf16 reg-staged, ds_write to swizzled slot
        for (int i = 0; i < 4; i++) {
            int si = i * 256 + t, row = si >> 3, ch = si & 7;
            const float* ap = act + (size_t)(act0 + row) * 1024 + k0 + ch * 8;
            float4v x = *(const float4v*)ap;
            float4v y = *(const float4v*)(ap + 4);
            uint4v o4 = { pkbf(x.x, x.y), pkbf(x.z, x.w),
                          pkbf(y.x, y.y), pkbf(y.z, y.w) };
            *(uint4v*)&actS[row * 64 + ((ch ^ (row & 7)) << 3)] = o4;
        }
        __syncthreads();
        for (int ks = 0; ks < 2; ks++) {
            bf16x8 af[4], bfr[4];
            for (int mi = 0; mi < 4; mi++)
                af[mi] = *(const bf16x8*)
                    &As[(wm * 64 + mi * 16 + lanelo) * 64 + ((ks * 32 + quad * 8) ^ rsw)];
            for (int ni = 0; ni < 4; ni++)
                bfr[ni] = *(const bf16x8*)
                    &Bs[(wn * 64 + ni * 16 + lanelo) * 64 + ((ks * 32 + quad * 8) ^ rsw)];
            for (int mi = 0; mi < 4; mi++)
                for (int ni = 0; ni < 4; ni++)
                    acc[mi][ni] = MFMA16(af[mi], bfr[ni], acc[mi][ni]);
        }
        __syncthreads();
    }

    for (int mi = 0; mi < 4; mi++)
        for (int ni = 0; ni < 4; ni++) {
            int col = n0 + wn * 64 + ni * 16 + lanelo;
            for (int rr = 0; rr < 4; rr++) {
                int row = m0 + wm * 64 + mi * 16 + quad * 4 + rr;
                out[(size_t)row * ldc + col] = f2bf(acc[mi][ni][rr]);
            }
        }
}

// ---------------------------------------------------------------------------
// O-projection: C[8192,1024] fp32 = A[8192,1024]bf16 @ Bt[1024,1024]bf16^T.
// v16: 256 blocks of 256x128, 512 threads (8 waves 4Mx2N, wave tile 64x64,
// acc[4][4] — v9 register profile).  Exactly 1 block/CU, zero tail.
// 2-phase dbuf (96KB LDS) + counted vmcnt(6): per iter {stage next (6 glds)
// -> vmcnt(6) -> barrier -> 32 MFMA/wave -> barrier}.  XCD decode keeps the
// 8 n-blocks of one 256-row A-panel co-XCD.
// ---------------------------------------------------------------------------
__global__ __launch_bounds__(512, 2) void gemm_bb(
    const unsigned short* __restrict__ A, const unsigned short* __restrict__ Bt,
    float* __restrict__ Cp, int M, int N, int K)
{
    __shared__ __align__(16) unsigned short As[2][256 * 64];  // 2x32 KB
    __shared__ __align__(16) unsigned short Bs[2][128 * 64];  // 2x16 KB

    const int t = threadIdx.x;                 // 0..511
    const int lane = t & 63, w = t >> 6;       // 8 waves
    const int lanelo = lane & 15, quad = lane >> 4;
    const int wm = w >> 1, wn = w & 1;         // 4M x 2N
    const int rsw = (lanelo & 7) << 3;

    const int d = blockIdx.x;                  // 0..255
    const int xcd = d & 7, s = d >> 3;         // s: 0..31
    const int m0 = ((((s >> 3) << 3) | xcd)) * 256;  // 32 m-panels -> XCD
    const int n0 = (s & 7) * 128;                    // 8 n-tiles

    auto stage = [&](int buf, int k0) {        // 6 glds / thread
        for (int i = 0; i < 4; i++) {          // A: 256x64 = 2048 units
            int idx = i * 512 + t, row = idx >> 3, ch = idx & 7;
            GLDS16(A + (size_t)(m0 + row) * K + k0 + ((ch ^ (row & 7)) << 3),
                   &As[buf][idx * 8]);
        }
        for (int i = 0; i < 2; i++) {          // B: 128x64 = 1024 units
            int idx = i * 512 + t, row = idx >> 3, ch = idx & 7;
            GLDS16(Bt + (size_t)(n0 + row) * K + k0 + ((ch ^ (row & 7)) << 3),
                   &Bs[buf][idx * 8]);
        }
    };

    float4v acc[4][4];
    for (int i = 0; i < 4; i++)
        for (int j = 0; j < 4; j++) acc[i][j] = (float4v)(0.f);

    stage(0, 0);
    for (int tt = 0; tt < 16; ++tt) {
        const int cur = tt & 1;
        if (tt + 1 < 16) {
            stage(cur ^ 1, (tt + 1) * 64);
            asm volatile("s_waitcnt vmcnt(6)" ::: "memory");   // cur's 6 done
        } else {
            asm volatile("s_waitcnt vmcnt(0)" ::: "memory");
        }
        __builtin_amdgcn_s_barrier();
        __builtin_amdgcn_sched_barrier(0);
        for (int ks = 0; ks < 2; ks++) {
            bf16x8 af[4], bfr[4];
            for (int mi = 0; mi < 4; mi++)
                af[mi] = *(const bf16x8*)
                    &As[cur][(wm * 64 + mi * 16 + lanelo) * 64 + ((ks * 32 + quad * 8) ^ rsw)];
            for (int ni = 0; ni < 4; ni++)
                bfr[ni] = *(const bf16x8*)
                    &Bs[cur][(wn * 64 + ni * 16 + lanelo) * 64 + ((ks * 32 + quad * 8) ^ rsw)];
            for (int mi = 0; mi < 4; mi++)
                for (int ni = 0; ni < 4; ni++)
                    acc[mi][ni] = MFMA16(af[mi], bfr[ni], acc[mi][ni]);
        }
        __builtin_amdgcn_sched_barrier(0);
        __builtin_amdgcn_s_barrier();                 // reads done before restage
    }

    for (int mi = 0; mi < 4; mi++)
        for (int ni = 0; ni < 4; ni++) {
            int col = n0 + wn * 64 + ni * 16 + lanelo;
            for (int r = 0; r < 4; r++) {
                int row = m0 + wm * 64 + mi * 16 + quad * 4 + r;
                Cp[(size_t)row * N + col] = acc[mi][ni][r];
            }
        }
}

// ---------------------------------------------------------------------------
// Flash causal attention — v12 (counted vmcnt + raw barriers), kept.
// ---------------------------------------------------------------------------
__global__ __launch_bounds__(256, 4) void attn_k(
    const unsigned short* __restrict__ Qb, const unsigned short* __restrict__ Kb,
    const unsigned short* __restrict__ Vt, unsigned short* __restrict__ Ob)
{
    __shared__ __align__(16) unsigned short Ks[2][64 * 64];
    __shared__ __align__(16) unsigned short Vs[2][64 * 64];
    __shared__ __align__(16) unsigned short Ps[4][16 * 64];

    const int t = threadIdx.x;
    const int lane = t & 63, w = t >> 6;
    const int lanelo = lane & 15, quad = lane >> 4;
    const int bh = blockIdx.x;                  // same (b,h) -> same XCD
    const int b = bh >> 4, h = bh & 15;

    unsigned short* pw = &Ps[w][0];
    const int rsw = (lanelo & 7) * 8;           // K/V read XOR (elems)
    const int l7 = lanelo & 7;                  // Ps chunk XOR key

    auto stage = [&](int buf, int kt) {         // 4 glds / thread
        for (int i = 0; i < 2; i++) {
            int idx = i * 256 + t, row = idx >> 3, ch = idx & 7;
            GLDS16(Kb + ((size_t)(b * 2048 + kt * 64 + row)) * 1024 + h * 64
                       + ((ch ^ (row & 7)) << 3),
                   &Ks[buf][idx * 8]);
        }
        for (int i = 0; i < 2; i++) {
            int idx = i * 256 + t, row = idx >> 3, ch = idx & 7;
            GLDS16(Vt + (size_t)(h * 64 + row) * 8192 + b * 2048 + kt * 64
                       + ((ch ^ (row & 7)) << 3),
                   &Vs[buf][idx * 8]);
        }
    };

    for (int half = 0; half < 2; half++) {
        const int qt = half ? blockIdx.y : 31 - blockIdx.y;
        const int qb = qt * 64;
        const int nkt = qt + 1;
        const int q = qb + w * 16 + lanelo;

        bf16x8 qf[2];
        {
            const unsigned short* qp = Qb + ((size_t)(b * 2048) + q) * 1024 + h * 64 + quad * 8;
            qf[0] = *(const bf16x8*)(qp);
            qf[1] = *(const bf16x8*)(qp + 32);
        }
        float4v o[4];
        for (int i = 0; i < 4; i++) o[i] = (float4v)(0.f);
        float m_ = -__builtin_inff(), l_ = 0.f;

        stage(0, 0);

        int cur = 0;
        for (int kt = 0; kt < nkt; kt++) {
            if (kt + 1 < nkt) {
                stage(cur ^ 1, kt + 1);                  // prefetch next tile
                asm volatile("s_waitcnt vmcnt(4)" ::: "memory");  // cur ready
            } else {
                asm volatile("s_waitcnt vmcnt(0)" ::: "memory");
            }
            __builtin_amdgcn_s_barrier();
            __builtin_amdgcn_sched_barrier(0);

            const unsigned short* ks = &Ks[cur][0];
            const unsigned short* vs = &Vs[cur][0];

            // S^T tiles: A = K rows (m=key), B = Q rows (n=q)
            float4v sc[4];
            for (int nt = 0; nt < 4; nt++) {
                sc[nt] = (float4v)(0.f);
                for (int c = 0; c < 2; c++) {
                    bf16x8 kf = *(const bf16x8*)
                        &ks[(nt * 16 + lanelo) * 64 + ((c * 32 + quad * 8) ^ rsw)];
                    sc[nt] = MFMA16(kf, qf[c], sc[nt]);
                }
            }
            if (kt == nkt - 1) {                        // only diagonal needs mask
                const int kb0 = qb + quad * 4;
                for (int nt = 0; nt < 4; nt++)
                    for (int r = 0; r < 4; r++)
                        if (kb0 + nt * 16 + r > q) sc[nt][r] = -__builtin_inff();
            }
            float mx = sc[0][0];
            for (int nt = 0; nt < 4; nt++)
                for (int r = 0; r < 4; r++) mx = fmaxf(mx, sc[nt][r]);
            mx = fmaxf(mx, __shfl_xor(mx, 16, 64));
            mx = fmaxf(mx, __shfl_xor(mx, 32, 64));
            if (!__all(mx <= m_ + 8.f)) {               // defer-max (T13), log2 dom
                float mnew = fmaxf(m_, mx);
                float alpha = exp2_fast(m_ - mnew);
                l_ *= alpha;
                for (int vt = 0; vt < 4; vt++)
                    for (int r = 0; r < 4; r++) o[vt][r] *= alpha;
                m_ = mnew;
            }
            float rs = 0.f;
            for (int nt = 0; nt < 4; nt++)
                for (int r = 0; r < 4; r++) {
                    float e = exp2_fast(sc[nt][r] - m_);
                    sc[nt][r] = e; rs += e;
                }
            rs += __shfl_xor(rs, 16, 64);
            rs += __shfl_xor(rs, 32, 64);
            l_ += rs;

            // P^T -> Ps (swizzled 16B chunks), b64 writes
            for (int nt = 0; nt < 4; nt++) {
                uint2v pv;
                pv.x = pkbf(sc[nt][0], sc[nt][1]);
                pv.y = pkbf(sc[nt][2], sc[nt][3]);
                *(uint2v*)((char*)pw + lanelo * 128
                           + ((((nt << 1) | (quad >> 1)) ^ l7) << 4)
                           + ((quad & 1) << 3)) = pv;
            }
            asm volatile("s_waitcnt lgkmcnt(0)" ::: "memory");
            __builtin_amdgcn_sched_barrier(0);
            // O^T += V^T P^T : A = V^T (m=dv), B = P (n=q)
            for (int c = 0; c < 2; c++) {
                bf16x8 pf = *(const bf16x8*)((const char*)pw + lanelo * 128
                                             + (((c * 4 + quad) ^ l7) << 4));
                for (int vt = 0; vt < 4; vt++) {
                    bf16x8 vf = *(const bf16x8*)
                        &vs[(vt * 16 + lanelo) * 64 + ((c * 32 + quad * 8) ^ rsw)];
                    o[vt] = MFMA16(vf, pf, o[vt]);
                }
            }
            __builtin_amdgcn_sched_barrier(0);
            __builtin_amdgcn_s_barrier();               // reads done before restage
            cur ^= 1;
        }

        // epilogue: normalize, transpose O^T -> O via swizzled Ps, 16B stores
        float inv = 1.0f / l_;
        for (int vt = 0; vt < 4; vt++) {
            uint2v ov;
            ov.x = pkbf(o[vt][0] * inv, o[vt][1] * inv);
            ov.y = pkbf(o[vt][2] * inv, o[vt][3] * inv);
            *(uint2v*)((char*)pw + lanelo * 128
                       + ((((vt << 1) | (quad >> 1)) ^ l7) << 4)
                       + ((quad & 1) << 3)) = ov;
        }
        asm volatile("s_waitcnt lgkmcnt(0)" ::: "memory");
        __builtin_amdgcn_sched_barrier(0);
        for (int i = 0; i < 2; i++) {
            int qr = i * 8 + (lane >> 3);
            int ch = lane & 7;
            ushort8v ov = *(const ushort8v*)((const char*)pw + qr * 128
                                             + ((ch ^ (qr & 7)) << 4));
            *(ushort8v*)(Ob + ((size_t)(b * 2048) + qb + w * 16 + qr) * 1024
                         + h * 64 + ch * 8) = ov;
        }
    }
}

// ---------------------------------------------------------------------------
extern "C" void kernel_launch(void* const* d_in, const int* in_sizes, int n_in,
                              void* d_out, int out_size, void* d_ws, size_t ws_size,
                              hipStream_t stream) {
    const float* queries = (const float*)d_in[0];
    const float* keys    = (const float*)d_in[1];
    const float* values  = (const float*)d_in[2];
    // d_in[3] = causal mask, handled analytically
    const float* W_Q = (const float*)d_in[4];
    const float* W_K = (const float*)d_in[5];
    const float* W_V = (const float*)d_in[6];
    const float* W_O = (const float*)d_in[7];

    const size_t SZ = (size_t)4 * 2048 * 1024;        // 8.4M elems
    const size_t WSZ = (size_t)1024 * 1024;
    unsigned short* Qb  = (unsigned short*)d_ws;
    unsigned short* Kb  = Qb + SZ;
    unsigned short* Vt  = Kb + SZ;                    // [1024][8192]
    unsigned short* Ab  = Vt + SZ;                    // attn output
    unsigned short* WQt = Ab + SZ;
    unsigned short* WKt = WQt + WSZ;
    unsigned short* WVt = WKt + WSZ;
    unsigned short* WOt = WVt + WSZ;                  // ~75.5 MB total

    dim3 blk(256);
    hipLaunchKernelGGL(transpose_w4, dim3(16, 16, 4), blk, 0, stream,
                       W_Q, W_K, W_V, W_O, WQt, WKt, WVt, WOt);

    hipLaunchKernelGGL(qkv_gemm, dim3(1536), blk, 0, stream,
                       queries, keys, values, WQt, WKt, WVt, Qb, Kb, Vt);

    hipLaunchKernelGGL(attn_k, dim3(64, 16), blk, 0, stream, Qb, Kb, Vt, Ab);

    hipLaunchKernelGGL(gemm_bb, dim3(256), dim3(512), 0, stream,
                       Ab, WOt, (float*)d_out, 8192, 1024, 1024);
}

// Round 16
// 311.940 us; speedup vs baseline: 1.1560x; 1.0360x over previous
//
#include <hip/hip_runtime.h>
#include <hip/hip_bf16.h>

// MHA fwd: B=4,S=2048,D=1024,H=16,DK=DV=64, causal.
// v17 = v12 EXACT REVERT (verified best: 313.4us, R11).
//  Session ladder: 477.6 -> 313.4 via attn XOR-swizzle (+23%), attn
//  pairing+dbuf pipeline (2.2x), fused QKV projection (kills 3 cvt passes),
//  XCD operand-locality remap (FETCH 289->74MB), GEMM LDS swizzle
//  (conflicts 1.9e7 -> 0).  v10-v16 probed: retiles, split-K, async-act,
//  counted-vmcnt grafts, persistent blocks, 512-thr tiles — all null or
//  regressive; 8-phase template does not fit N=1024 / fp32-act shapes
//  (half-machine at 256-wide tiles; reg-staged cvt breaks the schedule).
//  The 2-phase structure is at its measured plateau; this locks the best.

typedef __attribute__((ext_vector_type(8))) __bf16 bf16x8;
typedef __attribute__((ext_vector_type(8))) unsigned short ushort8v;
typedef __attribute__((ext_vector_type(4))) unsigned short ushort4v;
typedef __attribute__((ext_vector_type(4))) unsigned uint4v;
typedef __attribute__((ext_vector_type(2))) unsigned uint2v;
typedef __attribute__((ext_vector_type(4))) float float4v;

#define MFMA16(a, b, c) __builtin_amdgcn_mfma_f32_16x16x32_bf16((a), (b), (c), 0, 0, 0)
#define GLDS16(g, l)                                                     \
    __builtin_amdgcn_global_load_lds(                                    \
        (const __attribute__((address_space(1))) void*)(g),              \
        (__attribute__((address_space(3))) void*)(l), 16, 0, 0)

__device__ __forceinline__ unsigned short f2bf(float f) {   // RNE
    union { float f; unsigned u; } v; v.f = f;
    unsigned r = v.u + 0x7fffu + ((v.u >> 16) & 1u);
    return (unsigned short)(r >> 16);
}
__device__ __forceinline__ unsigned pkbf(float a, float b) { // 2xf32 -> 2xbf16
    union { float f; unsigned u; } x, y; x.f = a; y.f = b;
    return __builtin_amdgcn_perm(y.u + 0x8000u, x.u + 0x8000u, 0x07060302u);
}
__device__ __forceinline__ float exp2_fast(float x) {
#if __has_builtin(__builtin_amdgcn_exp2f)
    return __builtin_amdgcn_exp2f(x);
#else
    return __builtin_exp2f(x);
#endif
}

// ---------------------------------------------------------------------------
// 4x W [K=1024][N=1024] fp32 -> Wt [N][K] bf16 (scale folded), one launch
__global__ __launch_bounds__(256) void transpose_w4(
    const float* __restrict__ W0, const float* __restrict__ W1,
    const float* __restrict__ W2, const float* __restrict__ W3,
    unsigned short* __restrict__ T0, unsigned short* __restrict__ T1,
    unsigned short* __restrict__ T2, unsigned short* __restrict__ T3)
{
    __shared__ unsigned short T[64][72];
    const int z = blockIdx.z;
    const float* W = z == 0 ? W0 : z == 1 ? W1 : z == 2 ? W2 : W3;
    unsigned short* Wt = z == 0 ? T0 : z == 1 ? T1 : z == 2 ? T2 : T3;
    const float scale = (z == 1) ? 0.125f * 1.44269504088896f : 1.0f; // K: softmax*log2e
    const int t = threadIdx.x;
    const int n0 = blockIdx.x * 64, k0 = blockIdx.y * 64;
    for (int i = 0; i < 4; i++) {
        int idx = i * 256 + t, r = idx >> 4, c = (idx & 15) * 4;
        float4v v = *(const float4v*)&W[(size_t)(k0 + r) * 1024 + n0 + c];
        T[c + 0][r] = f2bf(v.x * scale); T[c + 1][r] = f2bf(v.y * scale);
        T[c + 2][r] = f2bf(v.z * scale); T[c + 3][r] = f2bf(v.w * scale);
    }
    __syncthreads();
    for (int i = 0; i < 4; i++) {
        int idx = i * 256 + t, r = idx >> 4, c = (idx & 15) * 4;
        ushort4v o; o.x = T[r][c]; o.y = T[r][c + 1]; o.z = T[r][c + 2]; o.w = T[r][c + 3];
        *(ushort4v*)&Wt[(size_t)(n0 + r) * 1024 + k0 + c] = o;
    }
}

// ---------------------------------------------------------------------------
// Grouped QKV projection — v9 VERBATIM (verified 107us, bank-conflicts 0).
// ---------------------------------------------------------------------------
__global__ __launch_bounds__(256) void qkv_gemm(
    const float* __restrict__ Aq, const float* __restrict__ Ak,
    const float* __restrict__ Av,
    const unsigned short* __restrict__ WQt, const unsigned short* __restrict__ WKt,
    const unsigned short* __restrict__ WVt,
    unsigned short* __restrict__ Qb, unsigned short* __restrict__ Kb,
    unsigned short* __restrict__ Vto)
{
    __shared__ __align__(16) unsigned short As[128 * 64];
    __shared__ __align__(16) unsigned short Bs[128 * 64];

    const int t = threadIdx.x;
    const int lane = t & 63, w = t >> 6;
    const int lanelo = lane & 15, quad = lane >> 4;
    const int wm = w >> 1, wn = w & 1;
    const int rsw = (lanelo & 7) << 3;     // read-side XOR (elements)

    const int d = blockIdx.x;
    const int xcd = d & 7;
    const int s = d >> 3;                  // 0..191
    const int group = s >> 6;              // 0,1,2
    const int u = s & 63;
    const bool vsw = (group == 2);

    const float* act; const unsigned short* wt; unsigned short* out;
    if (group == 0)      { act = Aq; wt = WQt; out = Qb; }
    else if (group == 1) { act = Ak; wt = WKt; out = Kb; }
    else                 { act = Av; wt = WVt; out = Vto; }

    const int big = (((u >> 3) << 3) | xcd) * 128;   // activation-panel tile
    const int sml = (u & 7) * 128;                   // other-operand tile
    int m0, n0, ldc;
    if (!vsw) { m0 = big; n0 = sml; ldc = 1024; }
    else      { n0 = big; m0 = sml; ldc = 8192; }
    const int act0 = vsw ? n0 : m0;      // activation tile row base
    const int wt0  = vsw ? m0 : n0;      // weight tile row base
    unsigned short* actS = vsw ? Bs : As;
    unsigned short* wtS  = vsw ? As : Bs;

    float4v acc[4][4];
    for (int i = 0; i < 4; i++)
        for (int j = 0; j < 4; j++) acc[i][j] = (float4v)(0.f);

    for (int k0 = 0; k0 < 1024; k0 += 64) {
        // weight tile via async glds, source pre-swizzled (linear LDS dest)
        for (int i = 0; i < 4; i++) {
            int idx = i * 256 + t, row = idx >> 3, ch = idx & 7;
            GLDS16(wt + (size_t)(wt0 + row) * 1024 + k0 + ((ch ^ (row & 7)) << 3),
                   &wtS[idx * 8]);
        }
        // activation tile: fp32 -> bf16 reg-staged, ds_write to swizzled slot
        for (int i = 0; i < 4; i++) {
            int si = i * 256 + t, row = si >> 3, ch = si & 7;
            const float* ap = act + (size_t)(act0 + row) * 1024 + k0 + ch * 8;
            float4v x = *(const float4v*)ap;
            float4v y = *(const float4v*)(ap + 4);
            uint4v o4 = { pkbf(x.x, x.y), pkbf(x.z, x.w),
                          pkbf(y.x, y.y), pkbf(y.z, y.w) };
            *(uint4v*)&actS[row * 64 + ((ch ^ (row & 7)) << 3)] = o4;
        }
        __syncthreads();
        for (int ks = 0; ks < 2; ks++) {
            bf16x8 af[4], bfr[4];
            for (int mi = 0; mi < 4; mi++)
                af[mi] = *(const bf16x8*)
                    &As[(wm * 64 + mi * 16 + lanelo) * 64 + ((ks * 32 + quad * 8) ^ rsw)];
            for (int ni = 0; ni < 4; ni++)
                bfr[ni] = *(const bf16x8*)
                    &Bs[(wn * 64 + ni * 16 + lanelo) * 64 + ((ks * 32 + quad * 8) ^ rsw)];
            for (int mi = 0; mi < 4; mi++)
                for (int ni = 0; ni < 4; ni++)
                    acc[mi][ni] = MFMA16(af[mi], bfr[ni], acc[mi][ni]);
        }
        __syncthreads();
    }

    for (int mi = 0; mi < 4; mi++)
        for (int ni = 0; ni < 4; ni++) {
            int col = n0 + wn * 64 + ni * 16 + lanelo;
            for (int rr = 0; rr < 4; rr++) {
                int row = m0 + wm * 64 + mi * 16 + quad * 4 + rr;
                out[(size_t)row * ldc + col] = f2bf(acc[mi][ni][rr]);
            }
        }
}

// ---------------------------------------------------------------------------
// O-projection (v12): 512 x 128x128, double-buffered (64KB), counted vmcnt:
// per iter {stage next (8 glds) -> vmcnt(8) -> barrier -> 32 MFMA -> barrier}.
// ---------------------------------------------------------------------------
__global__ __launch_bounds__(256) void gemm_bb(
    const unsigned short* __restrict__ A, const unsigned short* __restrict__ Bt,
    float* __restrict__ Cp, int M, int N, int K)
{
    __shared__ __align__(16) unsigned short As[2][128 * 64];
    __shared__ __align__(16) unsigned short Bs[2][128 * 64];

    const int t = threadIdx.x;
    const int lane = t & 63, w = t >> 6;
    const int lanelo = lane & 15, quad = lane >> 4;
    const int wm = w >> 1, wn = w & 1;
    const int rsw = (lanelo & 7) << 3;

    const int d = blockIdx.x;
    const int xcd = d & 7, s = d >> 3;               // s: 0..63
    const int m0 = ((((s >> 3) << 3) | xcd)) * 128;  // 64 m-tiles, panel->XCD
    const int n0 = (s & 7) * 128;                    // 8 n-tiles

    auto stage = [&](int buf, int k0) {              // 8 glds / thread
        for (int i = 0; i < 4; i++) {
            int idx = i * 256 + t, row = idx >> 3, ch = idx & 7;
            GLDS16(A + (size_t)(m0 + row) * K + k0 + ((ch ^ (row & 7)) << 3),
                   &As[buf][idx * 8]);
        }
        for (int i = 0; i < 4; i++) {
            int idx = i * 256 + t, row = idx >> 3, ch = idx & 7;
            GLDS16(Bt + (size_t)(n0 + row) * K + k0 + ((ch ^ (row & 7)) << 3),
                   &Bs[buf][idx * 8]);
        }
    };

    float4v acc[4][4];
    for (int i = 0; i < 4; i++)
        for (int j = 0; j < 4; j++) acc[i][j] = (float4v)(0.f);

    stage(0, 0);
    for (int tt = 0; tt < 16; ++tt) {
        const int cur = tt & 1;
        if (tt + 1 < 16) {
            stage(cur ^ 1, (tt + 1) * 64);
            asm volatile("s_waitcnt vmcnt(8)" ::: "memory");   // cur's 8 done
        } else {
            asm volatile("s_waitcnt vmcnt(0)" ::: "memory");
        }
        __builtin_amdgcn_s_barrier();
        __builtin_amdgcn_sched_barrier(0);
        for (int ks = 0; ks < 2; ks++) {
            bf16x8 af[4], bfr[4];
            for (int mi = 0; mi < 4; mi++)
                af[mi] = *(const bf16x8*)
                    &As[cur][(wm * 64 + mi * 16 + lanelo) * 64 + ((ks * 32 + quad * 8) ^ rsw)];
            for (int ni = 0; ni < 4; ni++)
                bfr[ni] = *(const bf16x8*)
                    &Bs[cur][(wn * 64 + ni * 16 + lanelo) * 64 + ((ks * 32 + quad * 8) ^ rsw)];
            for (int mi = 0; mi < 4; mi++)
                for (int ni = 0; ni < 4; ni++)
                    acc[mi][ni] = MFMA16(af[mi], bfr[ni], acc[mi][ni]);
        }
        __builtin_amdgcn_sched_barrier(0);
        __builtin_amdgcn_s_barrier();                 // reads done before restage
    }

    for (int mi = 0; mi < 4; mi++)
        for (int ni = 0; ni < 4; ni++) {
            int col = n0 + wn * 64 + ni * 16 + lanelo;
            for (int r = 0; r < 4; r++) {
                int row = m0 + wm * 64 + mi * 16 + quad * 4 + r;
                Cp[(size_t)row * N + col] = acc[mi][ni][r];
            }
        }
}

// ---------------------------------------------------------------------------
// Flash causal attention — v12 (counted vmcnt + raw barriers), verified 74us.
// ---------------------------------------------------------------------------
__global__ __launch_bounds__(256, 4) void attn_k(
    const unsigned short* __restrict__ Qb, const unsigned short* __restrict__ Kb,
    const unsigned short* __restrict__ Vt, unsigned short* __restrict__ Ob)
{
    __shared__ __align__(16) unsigned short Ks[2][64 * 64];
    __shared__ __align__(16) unsigned short Vs[2][64 * 64];
    __shared__ __align__(16) unsigned short Ps[4][16 * 64];

    const int t = threadIdx.x;
    const int lane = t & 63, w = t >> 6;
    const int lanelo = lane & 15, quad = lane >> 4;
    const int bh = blockIdx.x;                  // same (b,h) -> same XCD
    const int b = bh >> 4, h = bh & 15;

    unsigned short* pw = &Ps[w][0];
    const int rsw = (lanelo & 7) * 8;           // K/V read XOR (elems)
    const int l7 = lanelo & 7;                  // Ps chunk XOR key

    auto stage = [&](int buf, int kt) {         // 4 glds / thread
        for (int i = 0; i < 2; i++) {
            int idx = i * 256 + t, row = idx >> 3, ch = idx & 7;
            GLDS16(Kb + ((size_t)(b * 2048 + kt * 64 + row)) * 1024 + h * 64
                       + ((ch ^ (row & 7)) << 3),
                   &Ks[buf][idx * 8]);
        }
        for (int i = 0; i < 2; i++) {
            int idx = i * 256 + t, row = idx >> 3, ch = idx & 7;
            GLDS16(Vt + (size_t)(h * 64 + row) * 8192 + b * 2048 + kt * 64
                       + ((ch ^ (row & 7)) << 3),
                   &Vs[buf][idx * 8]);
        }
    };

    for (int half = 0; half < 2; half++) {
        const int qt = half ? blockIdx.y : 31 - blockIdx.y;
        const int qb = qt * 64;
        const int nkt = qt + 1;
        const int q = qb + w * 16 + lanelo;

        bf16x8 qf[2];
        {
            const unsigned short* qp = Qb + ((size_t)(b * 2048) + q) * 1024 + h * 64 + quad * 8;
            qf[0] = *(const bf16x8*)(qp);
            qf[1] = *(const bf16x8*)(qp + 32);
        }
        float4v o[4];
        for (int i = 0; i < 4; i++) o[i] = (float4v)(0.f);
        float m_ = -__builtin_inff(), l_ = 0.f;

        stage(0, 0);

        int cur = 0;
        for (int kt = 0; kt < nkt; kt++) {
            if (kt + 1 < nkt) {
                stage(cur ^ 1, kt + 1);                  // prefetch next tile
                asm volatile("s_waitcnt vmcnt(4)" ::: "memory");  // cur ready
            } else {
                asm volatile("s_waitcnt vmcnt(0)" ::: "memory");
            }
            __builtin_amdgcn_s_barrier();
            __builtin_amdgcn_sched_barrier(0);

            const unsigned short* ks = &Ks[cur][0];
            const unsigned short* vs = &Vs[cur][0];

            // S^T tiles: A = K rows (m=key), B = Q rows (n=q)
            float4v sc[4];
            for (int nt = 0; nt < 4; nt++) {
                sc[nt] = (float4v)(0.f);
                for (int c = 0; c < 2; c++) {
                    bf16x8 kf = *(const bf16x8*)
                        &ks[(nt * 16 + lanelo) * 64 + ((c * 32 + quad * 8) ^ rsw)];
                    sc[nt] = MFMA16(kf, qf[c], sc[nt]);
                }
            }
            if (kt == nkt - 1) {                        // only diagonal needs mask
                const int kb0 = qb + quad * 4;
                for (int nt = 0; nt < 4; nt++)
                    for (int r = 0; r < 4; r++)
                        if (kb0 + nt * 16 + r > q) sc[nt][r] = -__builtin_inff();
            }
            float mx = sc[0][0];
            for (int nt = 0; nt < 4; nt++)
                for (int r = 0; r < 4; r++) mx = fmaxf(mx, sc[nt][r]);
            mx = fmaxf(mx, __shfl_xor(mx, 16, 64));
            mx = fmaxf(mx, __shfl_xor(mx, 32, 64));
            if (!__all(mx <= m_ + 8.f)) {               // defer-max (T13), log2 dom
                float mnew = fmaxf(m_, mx);
                float alpha = exp2_fast(m_ - mnew);
                l_ *= alpha;
                for (int vt = 0; vt < 4; vt++)
                    for (int r = 0; r < 4; r++) o[vt][r] *= alpha;
                m_ = mnew;
            }
            float rs = 0.f;
            for (int nt = 0; nt < 4; nt++)
                for (int r = 0; r < 4; r++) {
                    float e = exp2_fast(sc[nt][r] - m_);
                    sc[nt][r] = e; rs += e;
                }
            rs += __shfl_xor(rs, 16, 64);
            rs += __shfl_xor(rs, 32, 64);
            l_ += rs;

            // P^T -> Ps (swizzled 16B chunks), b64 writes
            for (int nt = 0; nt < 4; nt++) {
                uint2v pv;
                pv.x = pkbf(sc[nt][0], sc[nt][1]);
                pv.y = pkbf(sc[nt][2], sc[nt][3]);
                *(uint2v*)((char*)pw + lanelo * 128
                           + ((((nt << 1) | (quad >> 1)) ^ l7) << 4)
                           + ((quad & 1) << 3)) = pv;
            }
            asm volatile("s_waitcnt lgkmcnt(0)" ::: "memory");
            __builtin_amdgcn_sched_barrier(0);
            // O^T += V^T P^T : A = V^T (m=dv), B = P (n=q)
            for (int c = 0; c < 2; c++) {
                bf16x8 pf = *(const bf16x8*)((const char*)pw + lanelo * 128
                                             + (((c * 4 + quad) ^ l7) << 4));
                for (int vt = 0; vt < 4; vt++) {
                    bf16x8 vf = *(const bf16x8*)
                        &vs[(vt * 16 + lanelo) * 64 + ((c * 32 + quad * 8) ^ rsw)];
                    o[vt] = MFMA16(vf, pf, o[vt]);
                }
            }
            __builtin_amdgcn_sched_barrier(0);
            __builtin_amdgcn_s_barrier();               // reads done before restage
            cur ^= 1;
        }

        // epilogue: normalize, transpose O^T -> O via swizzled Ps, 16B stores
        float inv = 1.0f / l_;
        for (int vt = 0; vt < 4; vt++) {
            uint2v ov;
            ov.x = pkbf(o[vt][0] * inv, o[vt][1] * inv);
            ov.y = pkbf(o[vt][2] * inv, o[vt][3] * inv);
            *(uint2v*)((char*)pw + lanelo * 128
                       + ((((vt << 1) | (quad >> 1)) ^ l7) << 4)
                       + ((quad & 1) << 3)) = ov;
        }
        asm volatile("s_waitcnt lgkmcnt(0)" ::: "memory");
        __builtin_amdgcn_sched_barrier(0);
        for (int i = 0; i < 2; i++) {
            int qr = i * 8 + (lane >> 3);
            int ch = lane & 7;
            ushort8v ov = *(const ushort8v*)((const char*)pw + qr * 128
                                             + ((ch ^ (qr & 7)) << 4));
            *(ushort8v*)(Ob + ((size_t)(b * 2048) + qb + w * 16 + qr) * 1024
                         + h * 64 + ch * 8) = ov;
        }
    }
}

// ---------------------------------------------------------------------------
extern "C" void kernel_launch(void* const* d_in, const int* in_sizes, int n_in,
                              void* d_out, int out_size, void* d_ws, size_t ws_size,
                              hipStream_t stream) {
    const float* queries = (const float*)d_in[0];
    const float* keys    = (const float*)d_in[1];
    const float* values  = (const float*)d_in[2];
    // d_in[3] = causal mask, handled analytically
    const float* W_Q = (const float*)d_in[4];
    const float* W_K = (const float*)d_in[5];
    const float* W_V = (const float*)d_in[6];
    const float* W_O = (const float*)d_in[7];

    const size_t SZ = (size_t)4 * 2048 * 1024;        // 8.4M elems
    const size_t WSZ = (size_t)1024 * 1024;
    unsigned short* Qb  = (unsigned short*)d_ws;
    unsigned short* Kb  = Qb + SZ;
    unsigned short* Vt  = Kb + SZ;                    // [1024][8192]
    unsigned short* Ab  = Vt + SZ;                    // attn output
    unsigned short* WQt = Ab + SZ;
    unsigned short* WKt = WQt + WSZ;
    unsigned short* WVt = WKt + WSZ;
    unsigned short* WOt = WVt + WSZ;                  // ~75.5 MB total

    dim3 blk(256);
    hipLaunchKernelGGL(transpose_w4, dim3(16, 16, 4), blk, 0, stream,
                       W_Q, W_K, W_V, W_O, WQt, WKt, WVt, WOt);

    hipLaunchKernelGGL(qkv_gemm, dim3(1536), blk, 0, stream,
                       queries, keys, values, WQt, WKt, WVt, Qb, Kb, Vt);

    hipLaunchKernelGGL(attn_k, dim3(64, 16), blk, 0, stream, Qb, Kb, Vt, Ab);

    hipLaunchKernelGGL(gemm_bb, dim3(512), blk, 0, stream,
                       Ab, WOt, (float*)d_out, 8192, 1024, 1024);
}